// Round 3
// baseline (506.838 us; speedup 1.0000x reference)
//
#include <hip/hip_runtime.h>
#include <hip/hip_bf16.h>
#include <stdint.h>

// Problem constants (from reference)
#define N_NODES 100000
#define N_EDGES 1600000
#define D_NODE  32
#define D_EDGE  16
#define D_IN    48   // D_NODE + D_EDGE
#define D_HID   64
#define D_OUT   32

// ---------------- workspace layout (bytes) ----------------
#define NFLAGS_OFF  ((size_t)0)         // 2 ints: {is_bf16, is_int64}
#define NW1T_OFF    ((size_t)64)        // fp32 W1^T [64][48]   (VALU fallback)
#define NB1_OFF     ((size_t)12352)     // fp32 [64]
#define NW2_OFF     ((size_t)12608)     // fp32 [64][32]        (VALU fallback)
#define NB2_OFF     ((size_t)20800)     // fp32 [32]
#define W1BF_OFF    ((size_t)24576)     // bf16 [n=64][k=64] n-major, k padded w/ 0
#define W2BF_OFF    ((size_t)32768)     // bf16 [n=32][k=64] n-major
#define COUNTS_OFF  ((size_t)65536)     // int [N_NODES]
#define OFFSETS_OFF ((size_t)466944)    // int [N_NODES+1]
#define CURSOR_OFF  ((size_t)917504)    // int [N_NODES]
#define BLKSUM_OFF  ((size_t)1376256)   // int [512]
#define MSG_OFF     ((size_t)8388608)   // message rows (bf16 64B or fp32 128B)

#define SCAN_NB 391   // ceil(100000/256)

typedef __attribute__((ext_vector_type(8))) short bf16x8;   // 8 bf16 = 4 VGPRs
typedef __attribute__((ext_vector_type(4))) float f32x4;

__device__ inline float bf2f(unsigned int u16) {
    return __uint_as_float(u16 << 16);
}
__device__ inline unsigned short f2bf_rne(float f) {
    unsigned int x = __float_as_uint(f);
    unsigned int r = (x + 0x7FFFu + ((x >> 16) & 1u)) >> 16;
    return (unsigned short)r;
}
__device__ inline float ld_f(const void* p, int i, int isbf) {
    if (isbf) return bf2f(((const unsigned short*)p)[i]);
    return ((const float*)p)[i];
}

// ---------------------------------------------------------------------------
// Prep: detect dtypes, build fp32 weights (fallback) + bf16 n-major weights
// (MFMA B-fragment source: w1b[n][k] = W1[k][n], k>=48 zero-padded).
// ---------------------------------------------------------------------------
__global__ void prep_kernel(const void* __restrict__ xq, const void* __restrict__ idxq,
                            const void* __restrict__ W1q, const void* __restrict__ b1q,
                            const void* __restrict__ W2q, const void* __restrict__ b2q,
                            char* __restrict__ ws) {
    __shared__ int s_isbf;
    if (threadIdx.x == 0) {
        const unsigned short* u = (const unsigned short*)xq;
        int isbf = 1;
        for (int i = 0; i < 64; ++i) {
            int e = (u[i] >> 7) & 0xFF;
            if (e >= 140) { isbf = 0; break; }
        }
        const int* w = (const int*)idxq;
        int is64 = 1;
        for (int i = 1; i < 64; i += 2) {
            if (w[i] != 0) { is64 = 0; break; }
        }
        int* flags = (int*)(ws + NFLAGS_OFF);
        flags[0] = isbf;
        flags[1] = is64;
        s_isbf = isbf;
    }
    __syncthreads();
    const int isbf = s_isbf;
    float* W1t = (float*)(ws + NW1T_OFF);
    float* b1  = (float*)(ws + NB1_OFF);
    float* W2  = (float*)(ws + NW2_OFF);
    float* b2  = (float*)(ws + NB2_OFF);
    unsigned short* w1b = (unsigned short*)(ws + W1BF_OFF);
    unsigned short* w2b = (unsigned short*)(ws + W2BF_OFF);

    for (int i = threadIdx.x; i < D_HID * D_IN; i += blockDim.x) {
        int j = i / D_IN, k = i % D_IN;           // W1t[j][k] = W1[k][j]
        W1t[i] = ld_f(W1q, k * D_HID + j, isbf);
    }
    for (int i = threadIdx.x; i < D_HID * D_OUT; i += blockDim.x)
        W2[i] = ld_f(W2q, i, isbf);
    if (threadIdx.x < D_HID) b1[threadIdx.x] = ld_f(b1q, threadIdx.x, isbf);
    if (threadIdx.x < D_OUT) b2[threadIdx.x] = ld_f(b2q, threadIdx.x, isbf);

    // bf16 n-major weights for MFMA B-fragments
    for (int i = threadIdx.x; i < D_HID * 64; i += blockDim.x) {
        int n = i >> 6, k = i & 63;
        float v = (k < D_IN) ? ld_f(W1q, k * D_HID + n, isbf) : 0.0f;
        w1b[i] = f2bf_rne(v);
    }
    for (int i = threadIdx.x; i < D_OUT * 64; i += blockDim.x) {
        int n = i >> 6, k = i & 63;
        w2b[i] = f2bf_rne(ld_f(W2q, k * D_OUT + n, isbf));
    }
}

// ---------------------------------------------------------------------------
// Histogram + scan (proven in round 2)
// ---------------------------------------------------------------------------
__global__ __launch_bounds__(256) void hist_kernel(const void* __restrict__ idxq,
                                                   char* __restrict__ ws) {
    const int is64 = ((const int*)(ws + NFLAGS_OFF))[1];
    const int e = blockIdx.x * 256 + threadIdx.x;
    int dst;
    if (is64) dst = (int)((const long long*)idxq)[e];
    else      dst = ((const int*)idxq)[e];
    atomicAdd((int*)(ws + COUNTS_OFF) + dst, 1);
}

__global__ __launch_bounds__(256) void scan_block_kernel(char* __restrict__ ws) {
    __shared__ int s[256];
    const int* counts = (const int*)(ws + COUNTS_OFF);
    int* offs   = (int*)(ws + OFFSETS_OFF);
    int* blksum = (int*)(ws + BLKSUM_OFF);
    const int t = threadIdx.x;
    const int i = blockIdx.x * 256 + t;
    int v = (i < N_NODES) ? counts[i] : 0;
    s[t] = v;
    __syncthreads();
    for (int d = 1; d < 256; d <<= 1) {
        int a = (t >= d) ? s[t - d] : 0;
        __syncthreads();
        s[t] += a;
        __syncthreads();
    }
    if (i < N_NODES) offs[i] = s[t] - v;      // local exclusive
    if (t == 255) blksum[blockIdx.x] = s[255];
}

__global__ __launch_bounds__(512) void scan_tops_kernel(char* __restrict__ ws) {
    __shared__ int s[512];
    int* blksum = (int*)(ws + BLKSUM_OFF);
    const int t = threadIdx.x;
    int v = (t < SCAN_NB) ? blksum[t] : 0;
    s[t] = v;
    __syncthreads();
    for (int d = 1; d < 512; d <<= 1) {
        int a = (t >= d) ? s[t - d] : 0;
        __syncthreads();
        s[t] += a;
        __syncthreads();
    }
    if (t < SCAN_NB) blksum[t] = s[t] - v;    // exclusive block offsets
}

__global__ __launch_bounds__(256) void scan_add_kernel(char* __restrict__ ws) {
    int* offs   = (int*)(ws + OFFSETS_OFF);
    int* cursor = (int*)(ws + CURSOR_OFF);
    const int* blksum = (const int*)(ws + BLKSUM_OFF);
    const int i = blockIdx.x * 256 + threadIdx.x;
    if (i < N_NODES) {
        int o = offs[i] + blksum[blockIdx.x];
        offs[i] = o;
        cursor[i] = o;
    }
    if (i == 0) offs[N_NODES] = N_EDGES;
}

// ---------------------------------------------------------------------------
// MFMA edge MLP (bf16 inputs only; early-exits otherwise).
// Block = 256 thr = 4 waves; wave owns 16 edges. A-fragments loaded straight
// from global in MFMA A-layout (A[m=lane&15][k=quad*8+j]):
//   chunk0 (k 0..31)  = x[src] bytes q*16..+16
//   chunk1 (k 32..63) = edge_attr bytes q*16 (q<2), zeros (q>=2; W1 rows
//                       48..63 are zero-padded too)
// h: C-layout -> LDS (stride 72 bf16: 2-way banks) -> A-layout reads.
// Layer-2 out -> LDS (stride 32 bf16) -> one dwordx4 row store per 4 lanes.
// ---------------------------------------------------------------------------
__global__ __launch_bounds__(256) void edge_mlp_mfma_kernel(
        const unsigned short* __restrict__ x,
        const void* __restrict__ idxq,
        const unsigned short* __restrict__ ea,
        const char* __restrict__ wsro,
        int* __restrict__ cursor,
        unsigned short* __restrict__ msg) {
    const int isbf = ((const int*)(wsro + NFLAGS_OFF))[0];
    if (!isbf) return;
    const int is64 = ((const int*)(wsro + NFLAGS_OFF))[1];

    __shared__ __align__(16) unsigned short h1[4][16][72];
    __shared__ __align__(16) unsigned short h2[4][16][32];

    const int tid = threadIdx.x;
    const int w   = tid >> 6;       // wave in block
    const int l   = tid & 63;       // lane
    const int m16 = l & 15;
    const int q   = l >> 4;

    const unsigned short* w1b = (const unsigned short*)(wsro + W1BF_OFF);
    const unsigned short* w2b = (const unsigned short*)(wsro + W2BF_OFF);
    const float* b1 = (const float*)(wsro + NB1_OFF);
    const float* b2 = (const float*)(wsro + NB2_OFF);

    // B-fragments: B[k=q*8+j][n=t*16+m16] = w?b[n][k] -> 16B contiguous loads
    bf16x8 w1f[4][2], w2f[2][2];
#pragma unroll
    for (int t = 0; t < 4; ++t)
#pragma unroll
        for (int c = 0; c < 2; ++c)
            w1f[t][c] = *(const bf16x8*)(w1b + ((t * 16 + m16) * 64 + c * 32 + q * 8));
#pragma unroll
    for (int t = 0; t < 2; ++t)
#pragma unroll
        for (int c = 0; c < 2; ++c)
            w2f[t][c] = *(const bf16x8*)(w2b + ((t * 16 + m16) * 64 + c * 32 + q * 8));

    const int e = blockIdx.x * 64 + w * 16 + m16;
    int dst, src;
    if (is64) {
        const long long* ip = (const long long*)idxq;
        dst = (int)ip[e];
        src = (int)ip[N_EDGES + e];
    } else {
        const int* ip = (const int*)idxq;
        dst = ip[e];
        src = ip[N_EDGES + e];
    }
    int pos = 0;
    if (q == 0) pos = atomicAdd(cursor + dst, 1);   // rank; latency hides under MFMA

    bf16x8 a0 = *(const bf16x8*)(x + (size_t)src * D_NODE + q * 8);
    bf16x8 a1;
#pragma unroll
    for (int i = 0; i < 8; ++i) a1[i] = 0;
    if (q < 2) a1 = *(const bf16x8*)(ea + (size_t)e * D_EDGE + q * 8);

    // ---- layer 1: [16x64] = relu([16x48(pad64)] @ [48x64] + b1) ----
    const float b1v[4] = { b1[m16], b1[16 + m16], b1[32 + m16], b1[48 + m16] };
#pragma unroll
    for (int t = 0; t < 4; ++t) {
        f32x4 c;
        c[0] = c[1] = c[2] = c[3] = b1v[t];
        c = __builtin_amdgcn_mfma_f32_16x16x32_bf16(a0, w1f[t][0], c, 0, 0, 0);
        c = __builtin_amdgcn_mfma_f32_16x16x32_bf16(a1, w1f[t][1], c, 0, 0, 0);
        // C layout: row(m)=q*4+r, col(n)=m16
#pragma unroll
        for (int r = 0; r < 4; ++r)
            h1[w][q * 4 + r][t * 16 + m16] = f2bf_rne(fmaxf(c[r], 0.0f));
    }
    __syncthreads();

    // h back in A-layout: lane(m16,q) reads h1[m16][c*32 + q*8 ..]
    bf16x8 a20 = *(const bf16x8*)(&h1[w][m16][q * 8]);
    bf16x8 a21 = *(const bf16x8*)(&h1[w][m16][32 + q * 8]);

    // ---- layer 2: [16x32] = [16x64] @ [64x32] + b2 ----
    const float b2v[2] = { b2[m16], b2[16 + m16] };
#pragma unroll
    for (int t = 0; t < 2; ++t) {
        f32x4 c;
        c[0] = c[1] = c[2] = c[3] = b2v[t];
        c = __builtin_amdgcn_mfma_f32_16x16x32_bf16(a20, w2f[t][0], c, 0, 0, 0);
        c = __builtin_amdgcn_mfma_f32_16x16x32_bf16(a21, w2f[t][1], c, 0, 0, 0);
#pragma unroll
        for (int r = 0; r < 4; ++r)
            h2[w][q * 4 + r][t * 16 + m16] = f2bf_rne(c[r]);
    }
    __syncthreads();

    // row store: 4 lanes * 16B = one 64B bf16 message row, scattered by rank
    const int mrow = l >> 2;
    const int sub  = l & 3;
    const int posm = __shfl(pos, mrow, 64);
    uint4 rowv = *(const uint4*)(&h2[w][mrow][sub * 8]);
    *(uint4*)(msg + (size_t)posm * D_OUT + sub * 8) = rowv;
}

// ---------------------------------------------------------------------------
// VALU fallback for fp32 inputs (early-exits if bf16). fp32 message rows.
// ---------------------------------------------------------------------------
__global__ __launch_bounds__(256) void edge_mlp_valu_f32_kernel(
        const float* __restrict__ x, const void* __restrict__ idxq,
        const float* __restrict__ ea,
        const char* __restrict__ wsro,
        int* __restrict__ cursor, float* __restrict__ msg) {
    const int isbf = ((const int*)(wsro + NFLAGS_OFF))[0];
    if (isbf) return;
    const int is64 = ((const int*)(wsro + NFLAGS_OFF))[1];

    const float* __restrict__ W1t = (const float*)(wsro + NW1T_OFF);
    const float* __restrict__ b1  = (const float*)(wsro + NB1_OFF);
    const float* __restrict__ W2  = (const float*)(wsro + NW2_OFF);
    const float* __restrict__ b2  = (const float*)(wsro + NB2_OFF);

    const int e = blockIdx.x * 256 + threadIdx.x;
    int dst, src;
    if (is64) {
        const long long* ip = (const long long*)idxq;
        dst = (int)ip[e];
        src = (int)ip[N_EDGES + e];
    } else {
        const int* ip = (const int*)idxq;
        dst = ip[e];
        src = ip[N_EDGES + e];
    }
    const int pos = atomicAdd(cursor + dst, 1);

    float inp[D_IN];
    const float4* xp = (const float4*)(x + (size_t)src * D_NODE);
#pragma unroll
    for (int t = 0; t < 8; ++t) {
        float4 v = xp[t];
        inp[t*4+0] = v.x; inp[t*4+1] = v.y; inp[t*4+2] = v.z; inp[t*4+3] = v.w;
    }
    const float4* ap = (const float4*)(ea + (size_t)e * D_EDGE);
#pragma unroll
    for (int t = 0; t < 4; ++t) {
        float4 v = ap[t];
        inp[32+t*4+0] = v.x; inp[32+t*4+1] = v.y; inp[32+t*4+2] = v.z; inp[32+t*4+3] = v.w;
    }

    float o[D_OUT];
#pragma unroll
    for (int m = 0; m < D_OUT; ++m) o[m] = b2[m];
    for (int j = 0; j < D_HID; ++j) {
        float s = b1[j];
#pragma unroll
        for (int k = 0; k < D_IN; ++k)
            s = fmaf(inp[k], W1t[j * D_IN + k], s);
        s = fmaxf(s, 0.0f);
#pragma unroll
        for (int m = 0; m < D_OUT; ++m)
            o[m] = fmaf(s, W2[j * D_OUT + m], o[m]);
    }

    float4* row = (float4*)(msg + (size_t)pos * D_OUT);
#pragma unroll
    for (int t = 0; t < 8; ++t) {
        float4 v;
        v.x = o[t*4+0]; v.y = o[t*4+1]; v.z = o[t*4+2]; v.w = o[t*4+3];
        row[t] = v;
    }
}

// ---------------------------------------------------------------------------
// Node-parallel reduce: half-wave per node, lane m sums component m over the
// node's contiguous rank-ordered rows. Row format follows the isbf flag.
// ---------------------------------------------------------------------------
__global__ __launch_bounds__(256) void reduce_kernel(
        const char* __restrict__ wsro, const char* __restrict__ msg,
        void* __restrict__ out) {
    const int isbf = ((const int*)(wsro + NFLAGS_OFF))[0];
    const int* offs = (const int*)(wsro + OFFSETS_OFF);
    const int node = (blockIdx.x * 256 + threadIdx.x) >> 5;
    const int m = threadIdx.x & 31;
    if (node >= N_NODES) return;
    const int lo = offs[node], hi = offs[node + 1];
    float s = 0.0f;
    if (isbf) {
        const unsigned short* p = (const unsigned short*)msg + (size_t)lo * 32 + m;
        int k = lo;
        for (; k + 1 < hi; k += 2) {
            float a = bf2f(p[0]), b = bf2f(p[32]);
            s += a + b;
            p += 64;
        }
        if (k < hi) s += bf2f(p[0]);
        ((unsigned short*)out)[(size_t)node * 32 + m] = f2bf_rne(s);
    } else {
        const float* p = (const float*)msg + (size_t)lo * 32 + m;
        int k = lo;
        for (; k + 1 < hi; k += 2) {
            float a = p[0], b = p[32];
            s += a + b;
            p += 64;
        }
        if (k < hi) s += p[0];
        ((float*)out)[(size_t)node * 32 + m] = s;
    }
}

extern "C" void kernel_launch(void* const* d_in, const int* in_sizes, int n_in,
                              void* d_out, int out_size, void* d_ws, size_t ws_size,
                              hipStream_t stream) {
    const void* x   = d_in[0];
    const void* idx = d_in[1];
    const void* ea  = d_in[2];
    const void* W1  = d_in[3];
    const void* b1  = d_in[4];
    const void* W2  = d_in[5];
    const void* b2  = d_in[6];
    char* ws = (char*)d_ws;

    // zero histogram counters only
    hipMemsetAsync(ws + COUNTS_OFF, 0, (size_t)N_NODES * 4, stream);

    hipLaunchKernelGGL(prep_kernel, dim3(1), dim3(256), 0, stream,
                       x, idx, W1, b1, W2, b2, ws);

    hipLaunchKernelGGL(hist_kernel, dim3(N_EDGES / 256), dim3(256), 0, stream, idx, ws);

    hipLaunchKernelGGL(scan_block_kernel, dim3(SCAN_NB), dim3(256), 0, stream, ws);
    hipLaunchKernelGGL(scan_tops_kernel,  dim3(1),       dim3(512), 0, stream, ws);
    hipLaunchKernelGGL(scan_add_kernel,   dim3(SCAN_NB), dim3(256), 0, stream, ws);

    // bf16 path (no-op if fp32 inputs)
    hipLaunchKernelGGL(edge_mlp_mfma_kernel, dim3(N_EDGES / 64), dim3(256), 0, stream,
                       (const unsigned short*)x, idx, (const unsigned short*)ea,
                       (const char*)ws, (int*)(ws + CURSOR_OFF),
                       (unsigned short*)(ws + MSG_OFF));

    // fp32 fallback (no-op if bf16 inputs)
    hipLaunchKernelGGL(edge_mlp_valu_f32_kernel, dim3(N_EDGES / 256), dim3(256), 0, stream,
                       (const float*)x, idx, (const float*)ea,
                       (const char*)ws, (int*)(ws + CURSOR_OFF),
                       (float*)(ws + MSG_OFF));

    hipLaunchKernelGGL(reduce_kernel, dim3((N_NODES * 32 + 255) / 256), dim3(256), 0, stream,
                       (const char*)ws, (const char*)(ws + MSG_OFF), d_out);
}

// Round 4
// 468.481 us; speedup vs baseline: 1.0819x; 1.0819x over previous
//
#include <hip/hip_runtime.h>
#include <hip/hip_bf16.h>
#include <stdint.h>

// Problem constants (from reference)
#define N_NODES 100000
#define N_EDGES 1600000
#define D_NODE  32
#define D_EDGE  16
#define D_IN    48   // D_NODE + D_EDGE
#define D_HID   64
#define D_OUT   32

// ---------------- workspace layout (bytes) ----------------
#define NFLAGS_OFF  ((size_t)0)         // 2 ints: {is_bf16, is_int64}
#define NB1_OFF     ((size_t)64)        // fp32 [64]
#define NB2_OFF     ((size_t)320)       // fp32 [32]
#define W1BF_OFF    ((size_t)1024)      // bf16 [n=64][k=64] n-major, k>=48 zero
#define W2BF_OFF    ((size_t)9216)      // bf16 [n=32][k=64] n-major
#define COUNTS_OFF  ((size_t)65536)     // int [N_NODES]
#define OFFSETS_OFF ((size_t)466944)    // int [N_NODES+1]
#define CURSOR_OFF  ((size_t)917504)    // int [N_NODES]
#define BLKSUM_OFF  ((size_t)1376256)   // int [512]
#define MSG_OFF     ((size_t)8388608)   // bf16 message rows, 64 B each

#define SCAN_NB 391   // ceil(100000/256)

typedef __attribute__((ext_vector_type(8))) short bf16x8;   // 8 bf16 = 4 VGPRs
typedef __attribute__((ext_vector_type(4))) float f32x4;

__device__ inline float bf2f(unsigned int u16) {
    return __uint_as_float(u16 << 16);
}
__device__ inline unsigned short f2bf_rne(float f) {
    unsigned int x = __float_as_uint(f);
    unsigned int r = (x + 0x7FFFu + ((x >> 16) & 1u)) >> 16;
    return (unsigned short)r;
}
__device__ inline float ld_f(const void* p, int i, int isbf) {
    if (isbf) return bf2f(((const unsigned short*)p)[i]);
    return ((const float*)p)[i];
}
__device__ inline bf16x8 pack_bf8(float4 v0, float4 v1) {
    bf16x8 r;
    r[0] = (short)f2bf_rne(v0.x); r[1] = (short)f2bf_rne(v0.y);
    r[2] = (short)f2bf_rne(v0.z); r[3] = (short)f2bf_rne(v0.w);
    r[4] = (short)f2bf_rne(v1.x); r[5] = (short)f2bf_rne(v1.y);
    r[6] = (short)f2bf_rne(v1.z); r[7] = (short)f2bf_rne(v1.w);
    return r;
}

// ---------------------------------------------------------------------------
// Prep: detect dtypes (fp32 data viewed as bf16 shows random exponent bits in
// low halfwords; int64 viewed as int32 has zero odd words), build bf16
// n-major weights for MFMA B-fragments + fp32 biases.
// ---------------------------------------------------------------------------
__global__ void prep_kernel(const void* __restrict__ xq, const void* __restrict__ idxq,
                            const void* __restrict__ W1q, const void* __restrict__ b1q,
                            const void* __restrict__ W2q, const void* __restrict__ b2q,
                            char* __restrict__ ws) {
    __shared__ int s_isbf;
    if (threadIdx.x == 0) {
        const unsigned short* u = (const unsigned short*)xq;
        int isbf = 1;
        for (int i = 0; i < 64; ++i) {
            int e = (u[i] >> 7) & 0xFF;
            if (e >= 140) { isbf = 0; break; }
        }
        const int* w = (const int*)idxq;
        int is64 = 1;
        for (int i = 1; i < 64; i += 2) {
            if (w[i] != 0) { is64 = 0; break; }
        }
        int* flags = (int*)(ws + NFLAGS_OFF);
        flags[0] = isbf;
        flags[1] = is64;
        s_isbf = isbf;
    }
    __syncthreads();
    const int isbf = s_isbf;
    float* b1 = (float*)(ws + NB1_OFF);
    float* b2 = (float*)(ws + NB2_OFF);
    unsigned short* w1b = (unsigned short*)(ws + W1BF_OFF);
    unsigned short* w2b = (unsigned short*)(ws + W2BF_OFF);

    if (threadIdx.x < D_HID) b1[threadIdx.x] = ld_f(b1q, threadIdx.x, isbf);
    if (threadIdx.x < D_OUT) b2[threadIdx.x] = ld_f(b2q, threadIdx.x, isbf);

    // w1b[n][k] = W1[k][n] (k>=48 zero);  w2b[n][k] = W2[k][n]
    for (int i = threadIdx.x; i < D_HID * 64; i += blockDim.x) {
        int n = i >> 6, k = i & 63;
        float v = (k < D_IN) ? ld_f(W1q, k * D_HID + n, isbf) : 0.0f;
        w1b[i] = f2bf_rne(v);
    }
    for (int i = threadIdx.x; i < D_OUT * 64; i += blockDim.x) {
        int n = i >> 6, k = i & 63;
        w2b[i] = f2bf_rne(ld_f(W2q, k * D_OUT + n, isbf));
    }
}

// ---------------------------------------------------------------------------
// Histogram + scan (proven rounds 2-3)
// ---------------------------------------------------------------------------
__global__ __launch_bounds__(256) void hist_kernel(const void* __restrict__ idxq,
                                                   char* __restrict__ ws) {
    const int is64 = ((const int*)(ws + NFLAGS_OFF))[1];
    const int e = blockIdx.x * 256 + threadIdx.x;
    int dst;
    if (is64) dst = (int)((const long long*)idxq)[e];
    else      dst = ((const int*)idxq)[e];
    atomicAdd((int*)(ws + COUNTS_OFF) + dst, 1);
}

__global__ __launch_bounds__(256) void scan_block_kernel(char* __restrict__ ws) {
    __shared__ int s[256];
    const int* counts = (const int*)(ws + COUNTS_OFF);
    int* offs   = (int*)(ws + OFFSETS_OFF);
    int* blksum = (int*)(ws + BLKSUM_OFF);
    const int t = threadIdx.x;
    const int i = blockIdx.x * 256 + t;
    int v = (i < N_NODES) ? counts[i] : 0;
    s[t] = v;
    __syncthreads();
    for (int d = 1; d < 256; d <<= 1) {
        int a = (t >= d) ? s[t - d] : 0;
        __syncthreads();
        s[t] += a;
        __syncthreads();
    }
    if (i < N_NODES) offs[i] = s[t] - v;      // local exclusive
    if (t == 255) blksum[blockIdx.x] = s[255];
}

__global__ __launch_bounds__(512) void scan_tops_kernel(char* __restrict__ ws) {
    __shared__ int s[512];
    int* blksum = (int*)(ws + BLKSUM_OFF);
    const int t = threadIdx.x;
    int v = (t < SCAN_NB) ? blksum[t] : 0;
    s[t] = v;
    __syncthreads();
    for (int d = 1; d < 512; d <<= 1) {
        int a = (t >= d) ? s[t - d] : 0;
        __syncthreads();
        s[t] += a;
        __syncthreads();
    }
    if (t < SCAN_NB) blksum[t] = s[t] - v;    // exclusive block offsets
}

__global__ __launch_bounds__(256) void scan_add_kernel(char* __restrict__ ws) {
    int* offs   = (int*)(ws + OFFSETS_OFF);
    int* cursor = (int*)(ws + CURSOR_OFF);
    const int* blksum = (const int*)(ws + BLKSUM_OFF);
    const int i = blockIdx.x * 256 + threadIdx.x;
    if (i < N_NODES) {
        int o = offs[i] + blksum[blockIdx.x];
        offs[i] = o;
        cursor[i] = o;
    }
    if (i == 0) offs[N_NODES] = N_EDGES;
}

// ---------------------------------------------------------------------------
// MFMA edge MLP, handles BOTH fp32 and bf16 inputs (wave-uniform branch;
// fp32 is converted to bf16 in registers). Block = 256 = 4 waves; each wave
// owns 16 edges. A-fragments (A[m=lane&15][k=quad*8+j]) come straight from
// global:  k 0..31 = x[src],  k 32..47 = edge_attr,  k 48..63 = 0 (W1 rows
// 48..63 zero-padded to match).
// h: C-layout -> LDS (stride 72 bf16: 2-way banks, free) -> A-layout.
// Layer-2 out -> LDS (stride 32) -> one dwordx4 per 4 lanes = 64 B row store
// at rank-ordered position (no fp32 atomics; one int atomic per edge).
// ---------------------------------------------------------------------------
__global__ __launch_bounds__(256) void edge_mlp_mfma_kernel(
        const void* __restrict__ xq,
        const void* __restrict__ idxq,
        const void* __restrict__ eaq,
        const char* __restrict__ wsro,
        int* __restrict__ cursor,
        unsigned short* __restrict__ msg) {
    const int isbf = ((const int*)(wsro + NFLAGS_OFF))[0];
    const int is64 = ((const int*)(wsro + NFLAGS_OFF))[1];

    __shared__ __align__(16) unsigned short h1[4][16][72];
    __shared__ __align__(16) unsigned short h2[4][16][32];

    const int tid = threadIdx.x;
    const int w   = tid >> 6;       // wave in block
    const int l   = tid & 63;       // lane
    const int m16 = l & 15;
    const int q   = l >> 4;

    const unsigned short* w1b = (const unsigned short*)(wsro + W1BF_OFF);
    const unsigned short* w2b = (const unsigned short*)(wsro + W2BF_OFF);
    const float* b1 = (const float*)(wsro + NB1_OFF);
    const float* b2 = (const float*)(wsro + NB2_OFF);

    // B-fragments: B[k=q*8+j][n=t*16+m16] = w?b[n][k] -> 16B contiguous loads
    bf16x8 w1f[4][2], w2f[2][2];
#pragma unroll
    for (int t = 0; t < 4; ++t)
#pragma unroll
        for (int c = 0; c < 2; ++c)
            w1f[t][c] = *(const bf16x8*)(w1b + ((t * 16 + m16) * 64 + c * 32 + q * 8));
#pragma unroll
    for (int t = 0; t < 2; ++t)
#pragma unroll
        for (int c = 0; c < 2; ++c)
            w2f[t][c] = *(const bf16x8*)(w2b + ((t * 16 + m16) * 64 + c * 32 + q * 8));

    const int e = blockIdx.x * 64 + w * 16 + m16;
    int dst, src;
    if (is64) {
        const long long* ip = (const long long*)idxq;
        dst = (int)ip[e];
        src = (int)ip[N_EDGES + e];
    } else {
        const int* ip = (const int*)idxq;
        dst = ip[e];
        src = ip[N_EDGES + e];
    }
    int pos = 0;
    if (q == 0) pos = atomicAdd(cursor + dst, 1);   // rank; latency hides under MFMA

    // A-fragments
    bf16x8 a0, a1;
#pragma unroll
    for (int i = 0; i < 8; ++i) a1[i] = 0;
    if (isbf) {
        const unsigned short* x = (const unsigned short*)xq;
        const unsigned short* ea = (const unsigned short*)eaq;
        a0 = *(const bf16x8*)(x + (size_t)src * D_NODE + q * 8);
        if (q < 2) a1 = *(const bf16x8*)(ea + (size_t)e * D_EDGE + q * 8);
    } else {
        const float* x = (const float*)xq;
        const float* ea = (const float*)eaq;
        const float4* xp = (const float4*)(x + (size_t)src * D_NODE + q * 8);
        a0 = pack_bf8(xp[0], xp[1]);
        if (q < 2) {
            const float4* ap = (const float4*)(ea + (size_t)e * D_EDGE + q * 8);
            a1 = pack_bf8(ap[0], ap[1]);
        }
    }

    // ---- layer 1: [16x64] = relu([16x48(pad64)] @ [48x64] + b1) ----
    const float b1v[4] = { b1[m16], b1[16 + m16], b1[32 + m16], b1[48 + m16] };
#pragma unroll
    for (int t = 0; t < 4; ++t) {
        f32x4 c;
        c[0] = c[1] = c[2] = c[3] = b1v[t];
        c = __builtin_amdgcn_mfma_f32_16x16x32_bf16(a0, w1f[t][0], c, 0, 0, 0);
        c = __builtin_amdgcn_mfma_f32_16x16x32_bf16(a1, w1f[t][1], c, 0, 0, 0);
        // C layout: row(m)=q*4+r, col(n)=m16
#pragma unroll
        for (int r = 0; r < 4; ++r)
            h1[w][q * 4 + r][t * 16 + m16] = f2bf_rne(fmaxf(c[r], 0.0f));
    }
    __syncthreads();

    // h back in A-layout: lane(m16,q) reads h1[m16][c*32 + q*8 ..]
    bf16x8 a20 = *(const bf16x8*)(&h1[w][m16][q * 8]);
    bf16x8 a21 = *(const bf16x8*)(&h1[w][m16][32 + q * 8]);

    // ---- layer 2: [16x32] = [16x64] @ [64x32] + b2 ----
    const float b2v[2] = { b2[m16], b2[16 + m16] };
#pragma unroll
    for (int t = 0; t < 2; ++t) {
        f32x4 c;
        c[0] = c[1] = c[2] = c[3] = b2v[t];
        c = __builtin_amdgcn_mfma_f32_16x16x32_bf16(a20, w2f[t][0], c, 0, 0, 0);
        c = __builtin_amdgcn_mfma_f32_16x16x32_bf16(a21, w2f[t][1], c, 0, 0, 0);
#pragma unroll
        for (int r = 0; r < 4; ++r)
            h2[w][q * 4 + r][t * 16 + m16] = f2bf_rne(c[r]);
    }
    __syncthreads();

    // row store: 4 lanes * 16B = one 64B bf16 message row, scattered by rank
    const int mrow = l >> 2;
    const int sub  = l & 3;
    const int posm = __shfl(pos, mrow, 64);
    uint4 rowv = *(const uint4*)(&h2[w][mrow][sub * 8]);
    *(uint4*)(msg + (size_t)posm * D_OUT + sub * 8) = rowv;
}

// ---------------------------------------------------------------------------
// Node-parallel reduce: half-wave per node, lane m sums component m over the
// node's contiguous rank-ordered bf16 rows; output dtype follows isbf flag.
// ---------------------------------------------------------------------------
__global__ __launch_bounds__(256) void reduce_kernel(
        const char* __restrict__ wsro, const unsigned short* __restrict__ msg,
        void* __restrict__ out) {
    const int isbf = ((const int*)(wsro + NFLAGS_OFF))[0];
    const int* offs = (const int*)(wsro + OFFSETS_OFF);
    const int node = (blockIdx.x * 256 + threadIdx.x) >> 5;
    const int m = threadIdx.x & 31;
    if (node >= N_NODES) return;
    const int lo = offs[node], hi = offs[node + 1];
    float s = 0.0f;
    const unsigned short* p = msg + (size_t)lo * 32 + m;
    int k = lo;
    for (; k + 1 < hi; k += 2) {            // 2x unroll: two independent loads
        float a = bf2f(p[0]), b = bf2f(p[32]);
        s += a + b;
        p += 64;
    }
    if (k < hi) s += bf2f(p[0]);
    if (isbf) ((unsigned short*)out)[(size_t)node * 32 + m] = f2bf_rne(s);
    else      ((float*)out)[(size_t)node * 32 + m] = s;
}

extern "C" void kernel_launch(void* const* d_in, const int* in_sizes, int n_in,
                              void* d_out, int out_size, void* d_ws, size_t ws_size,
                              hipStream_t stream) {
    const void* x   = d_in[0];
    const void* idx = d_in[1];
    const void* ea  = d_in[2];
    const void* W1  = d_in[3];
    const void* b1  = d_in[4];
    const void* W2  = d_in[5];
    const void* b2  = d_in[6];
    char* ws = (char*)d_ws;

    // zero histogram counters only
    hipMemsetAsync(ws + COUNTS_OFF, 0, (size_t)N_NODES * 4, stream);

    hipLaunchKernelGGL(prep_kernel, dim3(1), dim3(256), 0, stream,
                       x, idx, W1, b1, W2, b2, ws);

    hipLaunchKernelGGL(hist_kernel, dim3(N_EDGES / 256), dim3(256), 0, stream, idx, ws);

    hipLaunchKernelGGL(scan_block_kernel, dim3(SCAN_NB), dim3(256), 0, stream, ws);
    hipLaunchKernelGGL(scan_tops_kernel,  dim3(1),       dim3(512), 0, stream, ws);
    hipLaunchKernelGGL(scan_add_kernel,   dim3(SCAN_NB), dim3(256), 0, stream, ws);

    hipLaunchKernelGGL(edge_mlp_mfma_kernel, dim3(N_EDGES / 64), dim3(256), 0, stream,
                       x, idx, ea, (const char*)ws,
                       (int*)(ws + CURSOR_OFF), (unsigned short*)(ws + MSG_OFF));

    hipLaunchKernelGGL(reduce_kernel, dim3((N_NODES * 32 + 255) / 256), dim3(256), 0, stream,
                       (const char*)ws, (const unsigned short*)(ws + MSG_OFF), d_out);
}

// Round 5
// 394.041 us; speedup vs baseline: 1.2863x; 1.1889x over previous
//
#include <hip/hip_runtime.h>
#include <hip/hip_bf16.h>
#include <stdint.h>

// Problem constants (from reference)
#define N_NODES 100000
#define N_EDGES 1600000
#define D_NODE  32
#define D_EDGE  16
#define D_IN    48   // D_NODE + D_EDGE
#define D_HID   64
#define D_OUT   32

// ---------------- workspace layout (bytes) ----------------
#define NFLAGS_OFF  ((size_t)0)         // 2 ints: {is_bf16, is_int64}
#define NB1_OFF     ((size_t)64)        // fp32 [64]
#define NB2_OFF     ((size_t)320)       // fp32 [32]
#define W1BF_OFF    ((size_t)1024)      // bf16 [n=64][k=64] n-major, k>=48 zero
#define W2BF_OFF    ((size_t)9216)      // bf16 [n=32][k=64] n-major
#define COUNTS_OFF  ((size_t)65536)     // int [N_NODES]
#define OFFSETS_OFF ((size_t)466944)    // int [N_NODES+1]
#define BLKSUM_OFF  ((size_t)917504)    // int [512]
#define RANK_OFF    ((size_t)1048576)   // int [N_EDGES]  (6.4 MB, ends < 8 MB)
#define MSG_OFF     ((size_t)8388608)   // bf16 message rows, 64 B each

#define SCAN_NB 391   // ceil(100000/256)

typedef __attribute__((ext_vector_type(8))) short bf16x8;   // 8 bf16 = 4 VGPRs
typedef __attribute__((ext_vector_type(4))) float f32x4;

__device__ inline float bf2f(unsigned int u16) {
    return __uint_as_float(u16 << 16);
}
__device__ inline unsigned short f2bf_rne(float f) {
    unsigned int x = __float_as_uint(f);
    unsigned int r = (x + 0x7FFFu + ((x >> 16) & 1u)) >> 16;
    return (unsigned short)r;
}
__device__ inline float ld_f(const void* p, int i, int isbf) {
    if (isbf) return bf2f(((const unsigned short*)p)[i]);
    return ((const float*)p)[i];
}
__device__ inline bf16x8 pack_bf8(float4 v0, float4 v1) {
    bf16x8 r;
    r[0] = (short)f2bf_rne(v0.x); r[1] = (short)f2bf_rne(v0.y);
    r[2] = (short)f2bf_rne(v0.z); r[3] = (short)f2bf_rne(v0.w);
    r[4] = (short)f2bf_rne(v1.x); r[5] = (short)f2bf_rne(v1.y);
    r[6] = (short)f2bf_rne(v1.z); r[7] = (short)f2bf_rne(v1.w);
    return r;
}

// ---------------------------------------------------------------------------
// Prep: detect dtypes, build bf16 n-major weights + fp32 biases.
// ---------------------------------------------------------------------------
__global__ void prep_kernel(const void* __restrict__ xq, const void* __restrict__ idxq,
                            const void* __restrict__ W1q, const void* __restrict__ b1q,
                            const void* __restrict__ W2q, const void* __restrict__ b2q,
                            char* __restrict__ ws) {
    __shared__ int s_isbf;
    if (threadIdx.x == 0) {
        const unsigned short* u = (const unsigned short*)xq;
        int isbf = 1;
        for (int i = 0; i < 64; ++i) {
            int e = (u[i] >> 7) & 0xFF;
            if (e >= 140) { isbf = 0; break; }
        }
        const int* w = (const int*)idxq;
        int is64 = 1;
        for (int i = 1; i < 64; i += 2) {
            if (w[i] != 0) { is64 = 0; break; }
        }
        int* flags = (int*)(ws + NFLAGS_OFF);
        flags[0] = isbf;
        flags[1] = is64;
        s_isbf = isbf;
    }
    __syncthreads();
    const int isbf = s_isbf;
    float* b1 = (float*)(ws + NB1_OFF);
    float* b2 = (float*)(ws + NB2_OFF);
    unsigned short* w1b = (unsigned short*)(ws + W1BF_OFF);
    unsigned short* w2b = (unsigned short*)(ws + W2BF_OFF);

    if (threadIdx.x < D_HID) b1[threadIdx.x] = ld_f(b1q, threadIdx.x, isbf);
    if (threadIdx.x < D_OUT) b2[threadIdx.x] = ld_f(b2q, threadIdx.x, isbf);

    // w1b[n][k] = W1[k][n] (k>=48 zero);  w2b[n][k] = W2[k][n]
    for (int i = threadIdx.x; i < D_HID * 64; i += blockDim.x) {
        int n = i >> 6, k = i & 63;
        float v = (k < D_IN) ? ld_f(W1q, k * D_HID + n, isbf) : 0.0f;
        w1b[i] = f2bf_rne(v);
    }
    for (int i = threadIdx.x; i < D_OUT * 64; i += blockDim.x) {
        int n = i >> 6, k = i & 63;
        w2b[i] = f2bf_rne(ld_f(W2q, k * D_OUT + n, isbf));
    }
}

// ---------------------------------------------------------------------------
// Histogram + per-edge rank (atomic return value). Moves ALL atomics out of
// the MLP kernel; rank is a coalesced 4B/edge write.
// ---------------------------------------------------------------------------
__global__ __launch_bounds__(256) void hist_kernel(const void* __restrict__ idxq,
                                                   char* __restrict__ ws,
                                                   int* __restrict__ rankb) {
    const int is64 = ((const int*)(ws + NFLAGS_OFF))[1];
    const int e = blockIdx.x * 256 + threadIdx.x;
    int dst;
    if (is64) dst = (int)((const long long*)idxq)[e];
    else      dst = ((const int*)idxq)[e];
    rankb[e] = atomicAdd((int*)(ws + COUNTS_OFF) + dst, 1);
}

__global__ __launch_bounds__(256) void scan_block_kernel(char* __restrict__ ws) {
    __shared__ int s[256];
    const int* counts = (const int*)(ws + COUNTS_OFF);
    int* offs   = (int*)(ws + OFFSETS_OFF);
    int* blksum = (int*)(ws + BLKSUM_OFF);
    const int t = threadIdx.x;
    const int i = blockIdx.x * 256 + t;
    int v = (i < N_NODES) ? counts[i] : 0;
    s[t] = v;
    __syncthreads();
    for (int d = 1; d < 256; d <<= 1) {
        int a = (t >= d) ? s[t - d] : 0;
        __syncthreads();
        s[t] += a;
        __syncthreads();
    }
    if (i < N_NODES) offs[i] = s[t] - v;      // local exclusive
    if (t == 255) blksum[blockIdx.x] = s[255];
}

__global__ __launch_bounds__(512) void scan_tops_kernel(char* __restrict__ ws) {
    __shared__ int s[512];
    int* blksum = (int*)(ws + BLKSUM_OFF);
    const int t = threadIdx.x;
    int v = (t < SCAN_NB) ? blksum[t] : 0;
    s[t] = v;
    __syncthreads();
    for (int d = 1; d < 512; d <<= 1) {
        int a = (t >= d) ? s[t - d] : 0;
        __syncthreads();
        s[t] += a;
        __syncthreads();
    }
    if (t < SCAN_NB) blksum[t] = s[t] - v;    // exclusive block offsets
}

__global__ __launch_bounds__(256) void scan_add_kernel(char* __restrict__ ws) {
    int* offs   = (int*)(ws + OFFSETS_OFF);
    const int* blksum = (const int*)(ws + BLKSUM_OFF);
    const int i = blockIdx.x * 256 + threadIdx.x;
    if (i < N_NODES) offs[i] += blksum[blockIdx.x];
    if (i == 0) offs[N_NODES] = N_EDGES;
}

// ---------------------------------------------------------------------------
// MFMA edge MLP v2. 256 thr = 4 waves; each WAVE owns 64 edges = 4 groups
// of 16. No __syncthreads (h-tiles are wave-private; in-wave DS ordering
// suffices). No atomics (pos = offs[dst] + rank[e]). Weight fragments loaded
// once per wave. Inputs for all 4 groups issued up front for MLP latency
// hiding. fp32 or bf16 inputs (wave-uniform branch; fp32 converted in regs).
//   A-frag: A[m=lane&15][k=quad*8+j]; k 0..31 = x[src], 32..47 = ea, 48..63=0.
//   h: C-layout -> LDS stride-72 rows -> A-layout reads (2-way banks, free).
//   layer-2 out -> same LDS region -> one dwordx4 per 4 lanes = 64B row store.
// ---------------------------------------------------------------------------
__global__ __launch_bounds__(256) void edge_mlp_mfma_kernel(
        const void* __restrict__ xq,
        const void* __restrict__ idxq,
        const void* __restrict__ eaq,
        const char* __restrict__ wsro,
        const int* __restrict__ rankb,
        unsigned short* __restrict__ msg) {
    const int isbf = ((const int*)(wsro + NFLAGS_OFF))[0];
    const int is64 = ((const int*)(wsro + NFLAGS_OFF))[1];

    __shared__ __align__(16) unsigned short hbuf[4][4][16][72];   // [wave][group]

    const int tid = threadIdx.x;
    const int w   = tid >> 6;
    const int l   = tid & 63;
    const int m16 = l & 15;
    const int q   = l >> 4;

    const unsigned short* w1b = (const unsigned short*)(wsro + W1BF_OFF);
    const unsigned short* w2b = (const unsigned short*)(wsro + W2BF_OFF);
    const float* b1 = (const float*)(wsro + NB1_OFF);
    const float* b2 = (const float*)(wsro + NB2_OFF);
    const int* offs = (const int*)(wsro + OFFSETS_OFF);

    // B-fragments: B[k=q*8+j][n=t*16+m16] = w?b[n][k] -> 16B loads, once/wave
    bf16x8 w1f[4][2], w2f[2][2];
#pragma unroll
    for (int t = 0; t < 4; ++t)
#pragma unroll
        for (int c = 0; c < 2; ++c)
            w1f[t][c] = *(const bf16x8*)(w1b + ((t * 16 + m16) * 64 + c * 32 + q * 8));
#pragma unroll
    for (int t = 0; t < 2; ++t)
#pragma unroll
        for (int c = 0; c < 2; ++c)
            w2f[t][c] = *(const bf16x8*)(w2b + ((t * 16 + m16) * 64 + c * 32 + q * 8));

    const int eb = blockIdx.x * 256 + w * 64;

    // indices + rank + pos for all 4 groups
    int srcv[4], posv[4];
#pragma unroll
    for (int g = 0; g < 4; ++g) {
        const int e = eb + g * 16 + m16;
        int dst;
        if (is64) {
            const long long* ip = (const long long*)idxq;
            dst = (int)ip[e];
            srcv[g] = (int)ip[N_EDGES + e];
        } else {
            const int* ip = (const int*)idxq;
            dst = ip[e];
            srcv[g] = ip[N_EDGES + e];
        }
        posv[g] = offs[dst] + rankb[e];
    }

    // input fragments for all 4 groups (max memory parallelism)
    bf16x8 A0[4], A1[4];
#pragma unroll
    for (int g = 0; g < 4; ++g) {
        const int e = eb + g * 16 + m16;
#pragma unroll
        for (int i = 0; i < 8; ++i) A1[g][i] = 0;
        if (isbf) {
            const unsigned short* x  = (const unsigned short*)xq;
            const unsigned short* ea = (const unsigned short*)eaq;
            A0[g] = *(const bf16x8*)(x + (size_t)srcv[g] * D_NODE + q * 8);
            if (q < 2) A1[g] = *(const bf16x8*)(ea + (size_t)e * D_EDGE + q * 8);
        } else {
            const float* x  = (const float*)xq;
            const float* ea = (const float*)eaq;
            const float4* xp = (const float4*)(x + (size_t)srcv[g] * D_NODE + q * 8);
            A0[g] = pack_bf8(xp[0], xp[1]);
            if (q < 2) {
                const float4* ap = (const float4*)(ea + (size_t)e * D_EDGE + q * 8);
                A1[g] = pack_bf8(ap[0], ap[1]);
            }
        }
    }

    // ---- layer 1 for all groups: relu([16x48(pad64)] @ [48x64] + b1) ----
    const float b1v[4] = { b1[m16], b1[16 + m16], b1[32 + m16], b1[48 + m16] };
#pragma unroll
    for (int g = 0; g < 4; ++g) {
#pragma unroll
        for (int t = 0; t < 4; ++t) {
            f32x4 c;
            c[0] = c[1] = c[2] = c[3] = b1v[t];
            c = __builtin_amdgcn_mfma_f32_16x16x32_bf16(A0[g], w1f[t][0], c, 0, 0, 0);
            c = __builtin_amdgcn_mfma_f32_16x16x32_bf16(A1[g], w1f[t][1], c, 0, 0, 0);
            // C layout: row(m)=q*4+r, col(n)=m16
#pragma unroll
            for (int r = 0; r < 4; ++r)
                hbuf[w][g][q * 4 + r][t * 16 + m16] = f2bf_rne(fmaxf(c[r], 0.0f));
        }
    }

    // ---- layer 2 for all groups: [16x32] = [16x64] @ [64x32] + b2 ----
    // (in-wave DS ops are ordered: the a2 reads of group g complete before
    //  the h2 writes of group g touch the same region)
    const float b2v[2] = { b2[m16], b2[16 + m16] };
#pragma unroll
    for (int g = 0; g < 4; ++g) {
        bf16x8 a20 = *(const bf16x8*)(&hbuf[w][g][m16][q * 8]);
        bf16x8 a21 = *(const bf16x8*)(&hbuf[w][g][m16][32 + q * 8]);
#pragma unroll
        for (int t = 0; t < 2; ++t) {
            f32x4 c;
            c[0] = c[1] = c[2] = c[3] = b2v[t];
            c = __builtin_amdgcn_mfma_f32_16x16x32_bf16(a20, w2f[t][0], c, 0, 0, 0);
            c = __builtin_amdgcn_mfma_f32_16x16x32_bf16(a21, w2f[t][1], c, 0, 0, 0);
#pragma unroll
            for (int r = 0; r < 4; ++r)
                hbuf[w][g][q * 4 + r][t * 16 + m16] = f2bf_rne(c[r]);
        }
    }

    // ---- row stores: 4 lanes x 16B = one 64B bf16 row at rank position ----
    const int mrow = l >> 2;
    const int sub  = l & 3;
#pragma unroll
    for (int g = 0; g < 4; ++g) {
        const int posm = __shfl(posv[g], mrow, 64);
        uint4 rowv = *(const uint4*)(&hbuf[w][g][mrow][sub * 8]);
        *(uint4*)(msg + (size_t)posm * D_OUT + sub * 8) = rowv;
    }
}

// ---------------------------------------------------------------------------
// Node-parallel reduce: 16 lanes per node, lane handles 2 components via u32
// loads; 2-row unroll. Output dtype follows isbf flag.
// ---------------------------------------------------------------------------
__global__ __launch_bounds__(256) void reduce_kernel(
        const char* __restrict__ wsro, const unsigned short* __restrict__ msg,
        void* __restrict__ out) {
    const int isbf = ((const int*)(wsro + NFLAGS_OFF))[0];
    const int* offs = (const int*)(wsro + OFFSETS_OFF);
    const int t = blockIdx.x * 256 + threadIdx.x;
    const int node = t >> 4;
    if (node >= N_NODES) return;
    const int c2 = t & 15;                      // component pair 2*c2, 2*c2+1
    const int lo = offs[node], hi = offs[node + 1];
    float s0 = 0.0f, s1 = 0.0f;
    const unsigned int* p = (const unsigned int*)msg + (size_t)lo * 16 + c2;
    int k = lo;
    for (; k + 1 < hi; k += 2) {
        unsigned int a = p[0], b = p[16];
        s0 += __uint_as_float(a << 16) + __uint_as_float(b << 16);
        s1 += __uint_as_float(a & 0xFFFF0000u) + __uint_as_float(b & 0xFFFF0000u);
        p += 32;
    }
    if (k < hi) {
        unsigned int a = p[0];
        s0 += __uint_as_float(a << 16);
        s1 += __uint_as_float(a & 0xFFFF0000u);
    }
    if (isbf) {
        unsigned int pk = (unsigned int)f2bf_rne(s0) | ((unsigned int)f2bf_rne(s1) << 16);
        ((unsigned int*)out)[(size_t)node * 16 + c2] = pk;
    } else {
        float2 v; v.x = s0; v.y = s1;
        ((float2*)out)[(size_t)node * 16 + c2] = v;
    }
}

extern "C" void kernel_launch(void* const* d_in, const int* in_sizes, int n_in,
                              void* d_out, int out_size, void* d_ws, size_t ws_size,
                              hipStream_t stream) {
    const void* x   = d_in[0];
    const void* idx = d_in[1];
    const void* ea  = d_in[2];
    const void* W1  = d_in[3];
    const void* b1  = d_in[4];
    const void* W2  = d_in[5];
    const void* b2  = d_in[6];
    char* ws = (char*)d_ws;

    // zero histogram counters only
    hipMemsetAsync(ws + COUNTS_OFF, 0, (size_t)N_NODES * 4, stream);

    hipLaunchKernelGGL(prep_kernel, dim3(1), dim3(256), 0, stream,
                       x, idx, W1, b1, W2, b2, ws);

    hipLaunchKernelGGL(hist_kernel, dim3(N_EDGES / 256), dim3(256), 0, stream,
                       idx, ws, (int*)(ws + RANK_OFF));

    hipLaunchKernelGGL(scan_block_kernel, dim3(SCAN_NB), dim3(256), 0, stream, ws);
    hipLaunchKernelGGL(scan_tops_kernel,  dim3(1),       dim3(512), 0, stream, ws);
    hipLaunchKernelGGL(scan_add_kernel,   dim3(SCAN_NB), dim3(256), 0, stream, ws);

    hipLaunchKernelGGL(edge_mlp_mfma_kernel, dim3(N_EDGES / 256), dim3(256), 0, stream,
                       x, idx, ea, (const char*)ws,
                       (const int*)(ws + RANK_OFF), (unsigned short*)(ws + MSG_OFF));

    hipLaunchKernelGGL(reduce_kernel, dim3((N_NODES * 16 + 255) / 256), dim3(256), 0, stream,
                       (const char*)ws, (const unsigned short*)(ws + MSG_OFF), d_out);
}

// Round 6
// 380.790 us; speedup vs baseline: 1.3310x; 1.0348x over previous
//
#include <hip/hip_runtime.h>
#include <hip/hip_bf16.h>
#include <stdint.h>

// Problem constants (from reference)
#define N_NODES 100000
#define N_EDGES 1600000
#define D_NODE  32
#define D_EDGE  16
#define D_IN    48   // D_NODE + D_EDGE
#define D_HID   64
#define D_OUT   32

// ---------------- workspace layout (bytes) ----------------
#define NFLAGS_OFF  ((size_t)0)         // 2 ints: {is_bf16, is_int64}
#define NB1_OFF     ((size_t)64)        // fp32 [64]
#define NB2_OFF     ((size_t)320)       // fp32 [32]
#define W1BF_OFF    ((size_t)1024)      // bf16 [n=64][k=64] n-major, k>=48 zero
#define W2BF_OFF    ((size_t)9216)      // bf16 [n=32][k=64] n-major
#define COUNTS_OFF  ((size_t)65536)     // int [N_NODES]
#define OFFSETS_OFF ((size_t)466944)    // int [N_NODES+1]
#define BLKSUM_OFF  ((size_t)917504)    // int [512]
#define RANK_OFF    ((size_t)1048576)   // int [N_EDGES]  (6.4 MB, ends < 8 MB)
#define MSG_OFF     ((size_t)8388608)   // bf16 message rows, 64 B each

#define SCAN_NB 391   // ceil(100000/256)

typedef __attribute__((ext_vector_type(8))) short bf16x8;   // 8 bf16 = 4 VGPRs
typedef __attribute__((ext_vector_type(4))) float f32x4;

__device__ inline float bf2f(unsigned int u16) {
    return __uint_as_float(u16 << 16);
}
__device__ inline unsigned short f2bf_rne(float f) {
    unsigned int x = __float_as_uint(f);
    unsigned int r = (x + 0x7FFFu + ((x >> 16) & 1u)) >> 16;
    return (unsigned short)r;
}
// packed RNE fp32x2 -> bf16x2 (v_cvt_pk_bf16_f32 on gfx950)
__device__ inline unsigned int pk_bf2(float a, float b) {
    float2 f; f.x = a; f.y = b;
    __hip_bfloat162 h = __float22bfloat162_rn(f);
    return *reinterpret_cast<unsigned int*>(&h);
}
__device__ inline float ld_f(const void* p, int i, int isbf) {
    if (isbf) return bf2f(((const unsigned short*)p)[i]);
    return ((const float*)p)[i];
}
__device__ inline bf16x8 pack_bf8(float4 v0, float4 v1) {
    union { unsigned int u[4]; bf16x8 v; } r;
    r.u[0] = pk_bf2(v0.x, v0.y);
    r.u[1] = pk_bf2(v0.z, v0.w);
    r.u[2] = pk_bf2(v1.x, v1.y);
    r.u[3] = pk_bf2(v1.z, v1.w);
    return r.v;
}

// ---------------------------------------------------------------------------
// Prep: parallel dtype detection (ballot over 64 lanes; fp32 data viewed as
// bf16 shows exponent>=140 halfwords, int64 viewed as int32 has zero odd
// words), then bf16 n-major weights + fp32 biases.
// ---------------------------------------------------------------------------
__global__ void prep_kernel(const void* __restrict__ xq, const void* __restrict__ idxq,
                            const void* __restrict__ W1q, const void* __restrict__ b1q,
                            const void* __restrict__ W2q, const void* __restrict__ b2q,
                            char* __restrict__ ws) {
    __shared__ int s_isbf;
    const int t = threadIdx.x;
    if (t < 64) {   // wave 0 only
        unsigned short u = ((const unsigned short*)xq)[t];
        unsigned long long mb = __ballot(((u >> 7) & 0xFF) >= 140);
        int wodd = ((const int*)idxq)[2 * t + 1];
        unsigned long long mi = __ballot(wodd != 0);
        if (t == 0) {
            int* flags = (int*)(ws + NFLAGS_OFF);
            flags[0] = (mb == 0ULL);   // no big exponents -> genuine bf16
            flags[1] = (mi == 0ULL);   // all odd words zero -> int64
            s_isbf = (mb == 0ULL);
        }
    }
    __syncthreads();
    const int isbf = s_isbf;
    float* b1 = (float*)(ws + NB1_OFF);
    float* b2 = (float*)(ws + NB2_OFF);
    unsigned short* w1b = (unsigned short*)(ws + W1BF_OFF);
    unsigned short* w2b = (unsigned short*)(ws + W2BF_OFF);

    if (t < D_HID) b1[t] = ld_f(b1q, t, isbf);
    if (t < D_OUT) b2[t] = ld_f(b2q, t, isbf);

    // w1b[n][k] = W1[k][n] (k>=48 zero);  w2b[n][k] = W2[k][n]
    for (int i = t; i < D_HID * 64; i += blockDim.x) {
        int n = i >> 6, k = i & 63;
        float v = (k < D_IN) ? ld_f(W1q, k * D_HID + n, isbf) : 0.0f;
        w1b[i] = f2bf_rne(v);
    }
    for (int i = t; i < D_OUT * 64; i += blockDim.x) {
        int n = i >> 6, k = i & 63;
        w2b[i] = f2bf_rne(ld_f(W2q, k * D_OUT + n, isbf));
    }
}

// ---------------------------------------------------------------------------
// Histogram + per-edge rank (atomic return value); coalesced 4B/edge write.
// ---------------------------------------------------------------------------
__global__ __launch_bounds__(256) void hist_kernel(const void* __restrict__ idxq,
                                                   char* __restrict__ ws,
                                                   int* __restrict__ rankb) {
    const int is64 = ((const int*)(ws + NFLAGS_OFF))[1];
    const int e = blockIdx.x * 256 + threadIdx.x;
    int dst;
    if (is64) dst = (int)((const long long*)idxq)[e];
    else      dst = ((const int*)idxq)[e];
    rankb[e] = atomicAdd((int*)(ws + COUNTS_OFF) + dst, 1);
}

__global__ __launch_bounds__(256) void scan_block_kernel(char* __restrict__ ws) {
    __shared__ int s[256];
    const int* counts = (const int*)(ws + COUNTS_OFF);
    int* offs   = (int*)(ws + OFFSETS_OFF);
    int* blksum = (int*)(ws + BLKSUM_OFF);
    const int t = threadIdx.x;
    const int i = blockIdx.x * 256 + t;
    int v = (i < N_NODES) ? counts[i] : 0;
    s[t] = v;
    __syncthreads();
    for (int d = 1; d < 256; d <<= 1) {
        int a = (t >= d) ? s[t - d] : 0;
        __syncthreads();
        s[t] += a;
        __syncthreads();
    }
    if (i < N_NODES) offs[i] = s[t] - v;      // local exclusive
    if (t == 255) blksum[blockIdx.x] = s[255];
}

// scan_add with built-in top-level prefix: block b sums blksum[0..b-1] itself
// (391 ints from L2), then adds to its offsets. Saves the scan_tops launch.
__global__ __launch_bounds__(256) void scan_add_kernel(char* __restrict__ ws) {
    __shared__ int s[256];
    int* offs = (int*)(ws + OFFSETS_OFF);
    const int* blksum = (const int*)(ws + BLKSUM_OFF);
    const int t = threadIdx.x;
    const int b = blockIdx.x;
    int acc = 0;
    for (int j = t; j < b; j += 256) acc += blksum[j];
    s[t] = acc;
    __syncthreads();
    for (int d = 128; d > 0; d >>= 1) {
        if (t < d) s[t] += s[t + d];
        __syncthreads();
    }
    const int prefix = s[0];
    const int i = b * 256 + t;
    if (i < N_NODES) offs[i] += prefix;
    if (i == 0) offs[N_NODES] = N_EDGES;
}

// ---------------------------------------------------------------------------
// MFMA edge MLP v3. Block = 1 wave (64 thr); wave owns 64 edges = 4 groups of
// 16. LDS = TWO [16][72] buffers (4.6 KB/block -> LDS never caps occupancy),
// software-pipelined reuse; per-wave DS ordering makes it sync-free. No
// atomics (pos = offs[dst] + rank[e]). fp32 or bf16 inputs (wave-uniform
// branch; fp32 packed to bf16 via v_cvt_pk_bf16_f32).
//   A-frag: A[m=lane&15][k=quad*8+j]; k 0..31 = x[src], 32..47 = ea, 48..63=0.
//   h: C-layout -> LDS stride-72 rows -> A-layout b128 reads.
//   layer-2 out -> cols 0..31 of same buffer -> one dwordx4 per 4 lanes =
//   64 B row store at rank position.
// ---------------------------------------------------------------------------
__global__ __launch_bounds__(64) void edge_mlp_mfma_kernel(
        const void* __restrict__ xq,
        const void* __restrict__ idxq,
        const void* __restrict__ eaq,
        const char* __restrict__ wsro,
        const int* __restrict__ rankb,
        unsigned short* __restrict__ msg) {
    const int isbf = ((const int*)(wsro + NFLAGS_OFF))[0];
    const int is64 = ((const int*)(wsro + NFLAGS_OFF))[1];

    __shared__ __align__(16) unsigned short hbuf[2][16][72];

    const int l   = threadIdx.x;
    const int m16 = l & 15;
    const int q   = l >> 4;

    const unsigned short* w1b = (const unsigned short*)(wsro + W1BF_OFF);
    const unsigned short* w2b = (const unsigned short*)(wsro + W2BF_OFF);
    const float* b1 = (const float*)(wsro + NB1_OFF);
    const float* b2 = (const float*)(wsro + NB2_OFF);
    const int* offs = (const int*)(wsro + OFFSETS_OFF);

    // B-fragments: B[k=q*8+j][n=t*16+m16] = w?b[n][k] -> 16B loads (L1-hot)
    bf16x8 w1f[4][2], w2f[2][2];
#pragma unroll
    for (int t = 0; t < 4; ++t)
#pragma unroll
        for (int c = 0; c < 2; ++c)
            w1f[t][c] = *(const bf16x8*)(w1b + ((t * 16 + m16) * 64 + c * 32 + q * 8));
#pragma unroll
    for (int t = 0; t < 2; ++t)
#pragma unroll
        for (int c = 0; c < 2; ++c)
            w2f[t][c] = *(const bf16x8*)(w2b + ((t * 16 + m16) * 64 + c * 32 + q * 8));

    const int eb = blockIdx.x * 64;

    // indices + pos for all 4 groups (issued up front)
    int srcv[4], posv[4];
#pragma unroll
    for (int g = 0; g < 4; ++g) {
        const int e = eb + g * 16 + m16;
        int dst;
        if (is64) {
            const long long* ip = (const long long*)idxq;
            dst = (int)ip[e];
            srcv[g] = (int)ip[N_EDGES + e];
        } else {
            const int* ip = (const int*)idxq;
            dst = ip[e];
            srcv[g] = ip[N_EDGES + e];
        }
        posv[g] = offs[dst] + rankb[e];
    }

    // input fragments for all 4 groups (max memory parallelism)
    bf16x8 A0[4], A1[4];
#pragma unroll
    for (int g = 0; g < 4; ++g) {
        const int e = eb + g * 16 + m16;
#pragma unroll
        for (int i = 0; i < 8; ++i) A1[g][i] = 0;
        if (isbf) {
            const unsigned short* x  = (const unsigned short*)xq;
            const unsigned short* ea = (const unsigned short*)eaq;
            A0[g] = *(const bf16x8*)(x + (size_t)srcv[g] * D_NODE + q * 8);
            if (q < 2) A1[g] = *(const bf16x8*)(ea + (size_t)e * D_EDGE + q * 8);
        } else {
            const float* x  = (const float*)xq;
            const float* ea = (const float*)eaq;
            const float4* xp = (const float4*)(x + (size_t)srcv[g] * D_NODE + q * 8);
            A0[g] = pack_bf8(xp[0], xp[1]);
            if (q < 2) {
                const float4* ap = (const float4*)(ea + (size_t)e * D_EDGE + q * 8);
                A1[g] = pack_bf8(ap[0], ap[1]);
            }
        }
    }

    const float b1v[4] = { b1[m16], b1[16 + m16], b1[32 + m16], b1[48 + m16] };
    const float b2v[2] = { b2[m16], b2[16 + m16] };
    const int mrow = l >> 2;
    const int sub  = l & 3;

    // layer 1 for group g into buffer b
    auto L1 = [&](int g, int b) {
#pragma unroll
        for (int t = 0; t < 4; ++t) {
            f32x4 c;
            c[0] = c[1] = c[2] = c[3] = b1v[t];
            c = __builtin_amdgcn_mfma_f32_16x16x32_bf16(A0[g], w1f[t][0], c, 0, 0, 0);
            c = __builtin_amdgcn_mfma_f32_16x16x32_bf16(A1[g], w1f[t][1], c, 0, 0, 0);
            // C layout: row(m)=q*4+r, col(n)=t*16+m16
            unsigned int u0 = pk_bf2(fmaxf(c[0], 0.0f), fmaxf(c[1], 0.0f));
            unsigned int u1 = pk_bf2(fmaxf(c[2], 0.0f), fmaxf(c[3], 0.0f));
            hbuf[b][q * 4 + 0][t * 16 + m16] = (unsigned short)u0;
            hbuf[b][q * 4 + 1][t * 16 + m16] = (unsigned short)(u0 >> 16);
            hbuf[b][q * 4 + 2][t * 16 + m16] = (unsigned short)u1;
            hbuf[b][q * 4 + 3][t * 16 + m16] = (unsigned short)(u1 >> 16);
        }
    };
    // layer 2 + row store for group g from buffer b
    auto L2S = [&](int g, int b) {
        bf16x8 a20 = *(const bf16x8*)(&hbuf[b][m16][q * 8]);
        bf16x8 a21 = *(const bf16x8*)(&hbuf[b][m16][32 + q * 8]);
#pragma unroll
        for (int t = 0; t < 2; ++t) {
            f32x4 c;
            c[0] = c[1] = c[2] = c[3] = b2v[t];
            c = __builtin_amdgcn_mfma_f32_16x16x32_bf16(a20, w2f[t][0], c, 0, 0, 0);
            c = __builtin_amdgcn_mfma_f32_16x16x32_bf16(a21, w2f[t][1], c, 0, 0, 0);
            unsigned int u0 = pk_bf2(c[0], c[1]);
            unsigned int u1 = pk_bf2(c[2], c[3]);
            hbuf[b][q * 4 + 0][t * 16 + m16] = (unsigned short)u0;
            hbuf[b][q * 4 + 1][t * 16 + m16] = (unsigned short)(u0 >> 16);
            hbuf[b][q * 4 + 2][t * 16 + m16] = (unsigned short)u1;
            hbuf[b][q * 4 + 3][t * 16 + m16] = (unsigned short)(u1 >> 16);
        }
        const int posm = __shfl(posv[g], mrow, 64);
        uint4 rowv = *(const uint4*)(&hbuf[b][mrow][sub * 8]);
        *(uint4*)(msg + (size_t)posm * D_OUT + sub * 8) = rowv;
    };

    // software pipeline over 2 buffers; per-wave DS ordering = sync-free
    L1(0, 0);
    L1(1, 1);
    L2S(0, 0);
    L1(2, 0);
    L2S(1, 1);
    L1(3, 1);
    L2S(2, 0);
    L2S(3, 1);
}

// ---------------------------------------------------------------------------
// Node-parallel reduce: 16 lanes per node, lane handles 2 components via u32
// loads; 2-row unroll. Output dtype follows isbf flag.
// ---------------------------------------------------------------------------
__global__ __launch_bounds__(256) void reduce_kernel(
        const char* __restrict__ wsro, const unsigned short* __restrict__ msg,
        void* __restrict__ out) {
    const int isbf = ((const int*)(wsro + NFLAGS_OFF))[0];
    const int* offs = (const int*)(wsro + OFFSETS_OFF);
    const int t = blockIdx.x * 256 + threadIdx.x;
    const int node = t >> 4;
    if (node >= N_NODES) return;
    const int c2 = t & 15;                      // component pair 2*c2, 2*c2+1
    const int lo = offs[node], hi = offs[node + 1];
    float s0 = 0.0f, s1 = 0.0f;
    const unsigned int* p = (const unsigned int*)msg + (size_t)lo * 16 + c2;
    int k = lo;
    for (; k + 1 < hi; k += 2) {
        unsigned int a = p[0], b = p[16];
        s0 += __uint_as_float(a << 16) + __uint_as_float(b << 16);
        s1 += __uint_as_float(a & 0xFFFF0000u) + __uint_as_float(b & 0xFFFF0000u);
        p += 32;
    }
    if (k < hi) {
        unsigned int a = p[0];
        s0 += __uint_as_float(a << 16);
        s1 += __uint_as_float(a & 0xFFFF0000u);
    }
    if (isbf) {
        ((unsigned int*)out)[(size_t)node * 16 + c2] = pk_bf2(s0, s1);
    } else {
        float2 v; v.x = s0; v.y = s1;
        ((float2*)out)[(size_t)node * 16 + c2] = v;
    }
}

extern "C" void kernel_launch(void* const* d_in, const int* in_sizes, int n_in,
                              void* d_out, int out_size, void* d_ws, size_t ws_size,
                              hipStream_t stream) {
    const void* x   = d_in[0];
    const void* idx = d_in[1];
    const void* ea  = d_in[2];
    const void* W1  = d_in[3];
    const void* b1  = d_in[4];
    const void* W2  = d_in[5];
    const void* b2  = d_in[6];
    char* ws = (char*)d_ws;

    // zero histogram counters only
    hipMemsetAsync(ws + COUNTS_OFF, 0, (size_t)N_NODES * 4, stream);

    hipLaunchKernelGGL(prep_kernel, dim3(1), dim3(256), 0, stream,
                       x, idx, W1, b1, W2, b2, ws);

    hipLaunchKernelGGL(hist_kernel, dim3(N_EDGES / 256), dim3(256), 0, stream,
                       idx, ws, (int*)(ws + RANK_OFF));

    hipLaunchKernelGGL(scan_block_kernel, dim3(SCAN_NB), dim3(256), 0, stream, ws);
    hipLaunchKernelGGL(scan_add_kernel,   dim3(SCAN_NB), dim3(256), 0, stream, ws);

    hipLaunchKernelGGL(edge_mlp_mfma_kernel, dim3(N_EDGES / 64), dim3(64), 0, stream,
                       x, idx, ea, (const char*)ws,
                       (const int*)(ws + RANK_OFF), (unsigned short*)(ws + MSG_OFF));

    hipLaunchKernelGGL(reduce_kernel, dim3((N_NODES * 16 + 255) / 256), dim3(256), 0, stream,
                       (const char*)ws, (const unsigned short*)(ws + MSG_OFF), d_out);
}

// Round 7
// 369.449 us; speedup vs baseline: 1.3719x; 1.0307x over previous
//
#include <hip/hip_runtime.h>
#include <hip/hip_bf16.h>
#include <stdint.h>

// Problem constants (from reference)
#define N_NODES 100000
#define N_EDGES 1600000
#define D_NODE  32
#define D_EDGE  16
#define D_IN    48   // D_NODE + D_EDGE
#define D_HID   64
#define D_OUT   32

// ---------------- workspace layout (bytes) ----------------
#define NFLAGS_OFF  ((size_t)0)         // 2 ints: {is_bf16, is_int64}
#define NB1_OFF     ((size_t)64)        // fp32 [64]
#define NB2_OFF     ((size_t)320)       // fp32 [32]
#define W1BF_OFF    ((size_t)1024)      // bf16 [n=64][k=64] n-major, k>=48 zero
#define W2BF_OFF    ((size_t)9216)      // bf16 [n=32][k=64] n-major
#define COUNTS_OFF  ((size_t)65536)     // int [N_NODES]
#define OFFSETS_OFF ((size_t)466944)    // int [N_NODES+1]
#define BLKSUM_OFF  ((size_t)917504)    // int [512]
#define RANK_OFF    ((size_t)1048576)   // int [N_EDGES]  (6.4 MB, ends < 8 MB)
#define MSG_OFF     ((size_t)8388608)   // bf16 message rows, 64 B each

#define SCAN_NB 391   // ceil(100000/256)

typedef __attribute__((ext_vector_type(8))) short bf16x8;   // 8 bf16 = 4 VGPRs
typedef __attribute__((ext_vector_type(4))) float f32x4;

__device__ inline float bf2f(unsigned int u16) {
    return __uint_as_float(u16 << 16);
}
__device__ inline unsigned short f2bf_rne(float f) {
    unsigned int x = __float_as_uint(f);
    unsigned int r = (x + 0x7FFFu + ((x >> 16) & 1u)) >> 16;
    return (unsigned short)r;
}
// packed RNE fp32x2 -> bf16x2 (v_cvt_pk_bf16_f32 on gfx950)
__device__ inline unsigned int pk_bf2(float a, float b) {
    float2 f; f.x = a; f.y = b;
    __hip_bfloat162 h = __float22bfloat162_rn(f);
    return *reinterpret_cast<unsigned int*>(&h);
}
__device__ inline float ld_f(const void* p, int i, int isbf) {
    if (isbf) return bf2f(((const unsigned short*)p)[i]);
    return ((const float*)p)[i];
}
__device__ inline bf16x8 pack_bf8(float4 v0, float4 v1) {
    union { unsigned int u[4]; bf16x8 v; } r;
    r.u[0] = pk_bf2(v0.x, v0.y);
    r.u[1] = pk_bf2(v0.z, v0.w);
    r.u[2] = pk_bf2(v1.x, v1.y);
    r.u[3] = pk_bf2(v1.z, v1.w);
    return r.v;
}

// ---------------------------------------------------------------------------
// Prep (grid-wide): every block zeroes its slice of counts (replaces the
// hipMemsetAsync launch); block 0 additionally detects dtypes (ballot) and
// builds bf16 n-major weights + fp32 biases.
// ---------------------------------------------------------------------------
__global__ __launch_bounds__(256) void prep_kernel(
        const void* __restrict__ xq, const void* __restrict__ idxq,
        const void* __restrict__ W1q, const void* __restrict__ b1q,
        const void* __restrict__ W2q, const void* __restrict__ b2q,
        char* __restrict__ ws) {
    const int t = threadIdx.x;
    const int i0 = blockIdx.x * 256 + t;
    int* counts = (int*)(ws + COUNTS_OFF);
    if (i0 < N_NODES) counts[i0] = 0;
    if (blockIdx.x != 0) return;

    __shared__ int s_isbf;
    if (t < 64) {   // wave 0: parallel dtype detection
        unsigned short u = ((const unsigned short*)xq)[t];
        unsigned long long mb = __ballot(((u >> 7) & 0xFF) >= 140);
        int wodd = ((const int*)idxq)[2 * t + 1];
        unsigned long long mi = __ballot(wodd != 0);
        if (t == 0) {
            int* flags = (int*)(ws + NFLAGS_OFF);
            flags[0] = (mb == 0ULL);   // no big exponents -> genuine bf16
            flags[1] = (mi == 0ULL);   // all odd words zero -> int64
            s_isbf = (mb == 0ULL);
        }
    }
    __syncthreads();
    const int isbf = s_isbf;
    float* b1 = (float*)(ws + NB1_OFF);
    float* b2 = (float*)(ws + NB2_OFF);
    unsigned short* w1b = (unsigned short*)(ws + W1BF_OFF);
    unsigned short* w2b = (unsigned short*)(ws + W2BF_OFF);

    if (t < D_HID) b1[t] = ld_f(b1q, t, isbf);
    if (t < D_OUT) b2[t] = ld_f(b2q, t, isbf);

    // w1b[n][k] = W1[k][n] (k>=48 zero);  w2b[n][k] = W2[k][n]
    for (int i = t; i < D_HID * 64; i += 256) {
        int n = i >> 6, k = i & 63;
        float v = (k < D_IN) ? ld_f(W1q, k * D_HID + n, isbf) : 0.0f;
        w1b[i] = f2bf_rne(v);
    }
    for (int i = t; i < D_OUT * 64; i += 256) {
        int n = i >> 6, k = i & 63;
        w2b[i] = f2bf_rne(ld_f(W2q, k * D_OUT + n, isbf));
    }
}

// ---------------------------------------------------------------------------
// Histogram + per-edge rank (atomic return value); coalesced 4B/edge write.
// ---------------------------------------------------------------------------
__global__ __launch_bounds__(256) void hist_kernel(const void* __restrict__ idxq,
                                                   char* __restrict__ ws,
                                                   int* __restrict__ rankb) {
    const int is64 = ((const int*)(ws + NFLAGS_OFF))[1];
    const int e = blockIdx.x * 256 + threadIdx.x;
    int dst;
    if (is64) dst = (int)((const long long*)idxq)[e];
    else      dst = ((const int*)idxq)[e];
    rankb[e] = atomicAdd((int*)(ws + COUNTS_OFF) + dst, 1);
}

__global__ __launch_bounds__(256) void scan_block_kernel(char* __restrict__ ws) {
    __shared__ int s[256];
    const int* counts = (const int*)(ws + COUNTS_OFF);
    int* offs   = (int*)(ws + OFFSETS_OFF);
    int* blksum = (int*)(ws + BLKSUM_OFF);
    const int t = threadIdx.x;
    const int i = blockIdx.x * 256 + t;
    int v = (i < N_NODES) ? counts[i] : 0;
    s[t] = v;
    __syncthreads();
    for (int d = 1; d < 256; d <<= 1) {
        int a = (t >= d) ? s[t - d] : 0;
        __syncthreads();
        s[t] += a;
        __syncthreads();
    }
    if (i < N_NODES) offs[i] = s[t] - v;      // local exclusive
    if (t == 255) blksum[blockIdx.x] = s[255];
}

// scan_add with built-in top-level prefix: block b sums blksum[0..b-1] itself
// (391 ints from L2), then adds to its offsets.
__global__ __launch_bounds__(256) void scan_add_kernel(char* __restrict__ ws) {
    __shared__ int s[256];
    int* offs = (int*)(ws + OFFSETS_OFF);
    const int* blksum = (const int*)(ws + BLKSUM_OFF);
    const int t = threadIdx.x;
    const int b = blockIdx.x;
    int acc = 0;
    for (int j = t; j < b; j += 256) acc += blksum[j];
    s[t] = acc;
    __syncthreads();
    for (int d = 128; d > 0; d >>= 1) {
        if (t < d) s[t] += s[t + d];
        __syncthreads();
    }
    const int prefix = s[0];
    const int i = b * 256 + t;
    if (i < N_NODES) offs[i] += prefix;
    if (i == 0) offs[N_NODES] = N_EDGES;
}

// ---------------------------------------------------------------------------
// MFMA edge MLP v4. Block = 256 = 4 INDEPENDENT waves (no __syncthreads);
// wave owns 64 edges = 4 groups of 16, with private 2x[16][72] LDS buffers
// (18.4 KB/block -> 8 blocks/CU = 32 waves; VGPR~68 caps at 28 -- ~3x round-6
// concurrency vs the 16-workgroup/CU cap that bit single-wave blocks).
// Software-pipelined buffer reuse; per-wave DS ordering = sync-free.
// No atomics (pos = offs[dst] + rank[e]). fp32 or bf16 inputs (wave-uniform
// branch; fp32 packed via v_cvt_pk_bf16_f32). A1 loaded unconditionally with
// (q&1) addressing: lanes q>=2 feed k=48..63, whose W1 rows are ZERO, so the
// garbage multiplies to exactly 0 (branch + zero-init removed).
//   A-frag: A[m=lane&15][k=quad*8+j]; k 0..31 = x[src], 32..47 = ea, 48..63=0.
//   h: C-layout -> LDS stride-72 rows -> A-layout b128 reads.
//   layer-2 out -> same buffer -> one dwordx4 per 4 lanes = 64B row store.
// ---------------------------------------------------------------------------
__global__ __launch_bounds__(256) void edge_mlp_mfma_kernel(
        const void* __restrict__ xq,
        const void* __restrict__ idxq,
        const void* __restrict__ eaq,
        const char* __restrict__ wsro,
        const int* __restrict__ rankb,
        unsigned short* __restrict__ msg) {
    const int isbf = ((const int*)(wsro + NFLAGS_OFF))[0];
    const int is64 = ((const int*)(wsro + NFLAGS_OFF))[1];

    __shared__ __align__(16) unsigned short hbuf[4][2][16][72];

    const int w   = threadIdx.x >> 6;
    const int l   = threadIdx.x & 63;
    const int m16 = l & 15;
    const int q   = l >> 4;

    const unsigned short* w1b = (const unsigned short*)(wsro + W1BF_OFF);
    const unsigned short* w2b = (const unsigned short*)(wsro + W2BF_OFF);
    const float* b1 = (const float*)(wsro + NB1_OFF);
    const float* b2 = (const float*)(wsro + NB2_OFF);
    const int* offs = (const int*)(wsro + OFFSETS_OFF);

    // B-fragments: B[k=q*8+j][n=t*16+m16] = w?b[n][k] -> 16B loads (L1-hot)
    bf16x8 w1f[4][2], w2f[2][2];
#pragma unroll
    for (int t = 0; t < 4; ++t)
#pragma unroll
        for (int c = 0; c < 2; ++c)
            w1f[t][c] = *(const bf16x8*)(w1b + ((t * 16 + m16) * 64 + c * 32 + q * 8));
#pragma unroll
    for (int t = 0; t < 2; ++t)
#pragma unroll
        for (int c = 0; c < 2; ++c)
            w2f[t][c] = *(const bf16x8*)(w2b + ((t * 16 + m16) * 64 + c * 32 + q * 8));

    const int eb = blockIdx.x * 256 + w * 64;

    // indices + pos for all 4 groups (issued up front)
    int srcv[4], posv[4];
#pragma unroll
    for (int g = 0; g < 4; ++g) {
        const int e = eb + g * 16 + m16;
        int dst;
        if (is64) {
            const long long* ip = (const long long*)idxq;
            dst = (int)ip[e];
            srcv[g] = (int)ip[N_EDGES + e];
        } else {
            const int* ip = (const int*)idxq;
            dst = ip[e];
            srcv[g] = ip[N_EDGES + e];
        }
        posv[g] = offs[dst] + rankb[e];
    }

    // input fragments for all 4 groups (max memory parallelism)
    bf16x8 A0[4], A1[4];
#pragma unroll
    for (int g = 0; g < 4; ++g) {
        const int e = eb + g * 16 + m16;
        if (isbf) {
            const unsigned short* x  = (const unsigned short*)xq;
            const unsigned short* ea = (const unsigned short*)eaq;
            A0[g] = *(const bf16x8*)(x + (size_t)srcv[g] * D_NODE + q * 8);
            A1[g] = *(const bf16x8*)(ea + (size_t)e * D_EDGE + (q & 1) * 8);
        } else {
            const float* x  = (const float*)xq;
            const float* ea = (const float*)eaq;
            const float4* xp = (const float4*)(x + (size_t)srcv[g] * D_NODE + q * 8);
            A0[g] = pack_bf8(xp[0], xp[1]);
            const float4* ap = (const float4*)(ea + (size_t)e * D_EDGE + (q & 1) * 8);
            A1[g] = pack_bf8(ap[0], ap[1]);
        }
    }

    const float b1v[4] = { b1[m16], b1[16 + m16], b1[32 + m16], b1[48 + m16] };
    const float b2v[2] = { b2[m16], b2[16 + m16] };
    const int mrow = l >> 2;
    const int sub  = l & 3;

    // layer 1 for group g into buffer b
    auto L1 = [&](int g, int b) {
#pragma unroll
        for (int t = 0; t < 4; ++t) {
            f32x4 c;
            c[0] = c[1] = c[2] = c[3] = b1v[t];
            c = __builtin_amdgcn_mfma_f32_16x16x32_bf16(A0[g], w1f[t][0], c, 0, 0, 0);
            c = __builtin_amdgcn_mfma_f32_16x16x32_bf16(A1[g], w1f[t][1], c, 0, 0, 0);
            // C layout: row(m)=q*4+r, col(n)=t*16+m16
            unsigned int u0 = pk_bf2(fmaxf(c[0], 0.0f), fmaxf(c[1], 0.0f));
            unsigned int u1 = pk_bf2(fmaxf(c[2], 0.0f), fmaxf(c[3], 0.0f));
            hbuf[w][b][q * 4 + 0][t * 16 + m16] = (unsigned short)u0;
            hbuf[w][b][q * 4 + 1][t * 16 + m16] = (unsigned short)(u0 >> 16);
            hbuf[w][b][q * 4 + 2][t * 16 + m16] = (unsigned short)u1;
            hbuf[w][b][q * 4 + 3][t * 16 + m16] = (unsigned short)(u1 >> 16);
        }
    };
    // layer 2 + row store for group g from buffer b
    auto L2S = [&](int g, int b) {
        bf16x8 a20 = *(const bf16x8*)(&hbuf[w][b][m16][q * 8]);
        bf16x8 a21 = *(const bf16x8*)(&hbuf[w][b][m16][32 + q * 8]);
#pragma unroll
        for (int t = 0; t < 2; ++t) {
            f32x4 c;
            c[0] = c[1] = c[2] = c[3] = b2v[t];
            c = __builtin_amdgcn_mfma_f32_16x16x32_bf16(a20, w2f[t][0], c, 0, 0, 0);
            c = __builtin_amdgcn_mfma_f32_16x16x32_bf16(a21, w2f[t][1], c, 0, 0, 0);
            unsigned int u0 = pk_bf2(c[0], c[1]);
            unsigned int u1 = pk_bf2(c[2], c[3]);
            hbuf[w][b][q * 4 + 0][t * 16 + m16] = (unsigned short)u0;
            hbuf[w][b][q * 4 + 1][t * 16 + m16] = (unsigned short)(u0 >> 16);
            hbuf[w][b][q * 4 + 2][t * 16 + m16] = (unsigned short)u1;
            hbuf[w][b][q * 4 + 3][t * 16 + m16] = (unsigned short)(u1 >> 16);
        }
        const int posm = __shfl(posv[g], mrow, 64);
        uint4 rowv = *(const uint4*)(&hbuf[w][b][mrow][sub * 8]);
        *(uint4*)(msg + (size_t)posm * D_OUT + sub * 8) = rowv;
    };

    // software pipeline over 2 buffers; per-wave DS ordering = sync-free
    L1(0, 0);
    L1(1, 1);
    L2S(0, 0);
    L1(2, 0);
    L2S(1, 1);
    L1(3, 1);
    L2S(2, 0);
    L2S(3, 1);
}

// ---------------------------------------------------------------------------
// Node-parallel reduce: 16 lanes per node, lane handles 2 components via u32
// loads; 2-row unroll. Output dtype follows isbf flag.
// ---------------------------------------------------------------------------
__global__ __launch_bounds__(256) void reduce_kernel(
        const char* __restrict__ wsro, const unsigned short* __restrict__ msg,
        void* __restrict__ out) {
    const int isbf = ((const int*)(wsro + NFLAGS_OFF))[0];
    const int* offs = (const int*)(wsro + OFFSETS_OFF);
    const int t = blockIdx.x * 256 + threadIdx.x;
    const int node = t >> 4;
    if (node >= N_NODES) return;
    const int c2 = t & 15;                      // component pair 2*c2, 2*c2+1
    const int lo = offs[node], hi = offs[node + 1];
    float s0 = 0.0f, s1 = 0.0f;
    const unsigned int* p = (const unsigned int*)msg + (size_t)lo * 16 + c2;
    int k = lo;
    for (; k + 1 < hi; k += 2) {
        unsigned int a = p[0], b = p[16];
        s0 += __uint_as_float(a << 16) + __uint_as_float(b << 16);
        s1 += __uint_as_float(a & 0xFFFF0000u) + __uint_as_float(b & 0xFFFF0000u);
        p += 32;
    }
    if (k < hi) {
        unsigned int a = p[0];
        s0 += __uint_as_float(a << 16);
        s1 += __uint_as_float(a & 0xFFFF0000u);
    }
    if (isbf) {
        ((unsigned int*)out)[(size_t)node * 16 + c2] = pk_bf2(s0, s1);
    } else {
        float2 v; v.x = s0; v.y = s1;
        ((float2*)out)[(size_t)node * 16 + c2] = v;
    }
}

extern "C" void kernel_launch(void* const* d_in, const int* in_sizes, int n_in,
                              void* d_out, int out_size, void* d_ws, size_t ws_size,
                              hipStream_t stream) {
    const void* x   = d_in[0];
    const void* idx = d_in[1];
    const void* ea  = d_in[2];
    const void* W1  = d_in[3];
    const void* b1  = d_in[4];
    const void* W2  = d_in[5];
    const void* b2  = d_in[6];
    char* ws = (char*)d_ws;

    hipLaunchKernelGGL(prep_kernel, dim3(SCAN_NB), dim3(256), 0, stream,
                       x, idx, W1, b1, W2, b2, ws);

    hipLaunchKernelGGL(hist_kernel, dim3(N_EDGES / 256), dim3(256), 0, stream,
                       idx, ws, (int*)(ws + RANK_OFF));

    hipLaunchKernelGGL(scan_block_kernel, dim3(SCAN_NB), dim3(256), 0, stream, ws);
    hipLaunchKernelGGL(scan_add_kernel,   dim3(SCAN_NB), dim3(256), 0, stream, ws);

    hipLaunchKernelGGL(edge_mlp_mfma_kernel, dim3(N_EDGES / 256), dim3(256), 0, stream,
                       x, idx, ea, (const char*)ws,
                       (const int*)(ws + RANK_OFF), (unsigned short*)(ws + MSG_OFF));

    hipLaunchKernelGGL(reduce_kernel, dim3((N_NODES * 16 + 255) / 256), dim3(256), 0, stream,
                       (const char*)ws, (const unsigned short*)(ws + MSG_OFF), d_out);
}